// Round 16
// baseline (211.477 us; speedup 1.0000x reference)
//
#include <hip/hip_runtime.h>
#include <math.h>
#include <stdint.h>
#include <limits.h>

#define NPTS 32768
#define DIM  256
#define KCB  4096
#define NQ   (NPTS*DIM)

#define EPSN    1e-12f
#define MARGIN1 6.0e-4f
#define F16MIN  6.103515625e-05f
#define CAPB    4096

typedef __attribute__((ext_vector_type(8))) _Float16 f16x8;
typedef __attribute__((ext_vector_type(4))) _Float16 f16x4;
typedef __attribute__((ext_vector_type(4))) float    f32x4;

// ws layout (byte offsets).
// [0,2MB): EH0 f16 codebook (phase1) -> later overwritten by embT lower half
// [2MB,4MB): TRI (phase1 out, merge in) -> later overwritten by embT upper half
#define WS_EH0   0u
#define WS_TRI   2097152u
#define WS_EMBT  0u
#define WS_SUME  4194304u
#define WS_EINV  4210688u
#define WS_XINV  4227072u
#define WS_IDX   4358144u
#define WS_RCA   4489216u
#define WS_RLA   4489232u
#define WS_RCB   4751376u
#define WS_RLB   4751392u
#define WS_BEST  4882464u
#define WS_LOSSP 4915232u

__device__ inline unsigned fbits(float f){ union{float f;unsigned u;}v; v.f=f; return v.u; }
__device__ inline float bitsf(unsigned u){ union{float f;unsigned u;}v; v.u=u; return v.f; }
__device__ inline uint64_t dbits(double d){ union{double d;uint64_t u;}v; v.d=d; return v.u; }
__device__ inline _Float16 g16(float v){
    return (fabsf(v) < F16MIN) ? (_Float16)0.0f : (_Float16)v;
}
__device__ inline void gload16(const void* src, void* lds){
    __builtin_amdgcn_global_load_lds((const __attribute__((address_space(1))) void*)src,
                                     (__attribute__((address_space(3))) void*)lds, 16, 0, 0);
}

__global__ void k_init(int* rca, int* rcb) {
    if (threadIdx.x == 0) { *rca = 0; *rcb = 0; }
}

__global__ __launch_bounds__(256) void k_norm_x(const float* __restrict__ x,
                                                float* __restrict__ xinv) {
    int w = threadIdx.x >> 6, l = threadIdx.x & 63;
    int row = blockIdx.x * 4 + w;
    float4 v = ((const float4*)x)[row * 64 + l];
    float s = v.x*v.x + v.y*v.y + v.z*v.z + v.w*v.w;
    #pragma unroll
    for (int o = 32; o; o >>= 1) s += __shfl_xor(s, o);
    if (l == 0) xinv[row] = 1.0f / fmaxf(sqrtf(s), EPSN);
}

__global__ __launch_bounds__(256) void k_norm_e(const float* __restrict__ e,
                                                _Float16* __restrict__ eh0,
                                                float* __restrict__ sume,
                                                float* __restrict__ einv) {
    int w = threadIdx.x >> 6, l = threadIdx.x & 63;
    int row = blockIdx.x * 4 + w;
    float4 v = ((const float4*)e)[row * 64 + l];
    float s = v.x*v.x + v.y*v.y + v.z*v.z + v.w*v.w;
    #pragma unroll
    for (int o = 32; o; o >>= 1) s += __shfl_xor(s, o);
    float inv = 1.0f / fmaxf(sqrtf(s), EPSN);
    float4 n = make_float4(v.x*inv, v.y*inv, v.z*inv, v.w*inv);
    f16x4 h0; h0[0]=g16(n.x); h0[1]=g16(n.y); h0[2]=g16(n.z); h0[3]=g16(n.w);
    ((f16x4*)eh0)[row * 64 + l] = h0;
    float s2 = n.x*n.x + n.y*n.y + n.z*n.z + n.w*n.w;
    #pragma unroll
    for (int o = 32; o; o >>= 1) s2 += __shfl_xor(s2, o);
    if (l == 0) { sume[row] = s2; einv[row] = inv; }
}

// tier 1: swapped-operand f16 MFMA argmin, dhl-major conflict-free LDS,
// BRANCHLESS max-dot top-3 tracking (no divergent insert — round-15 PM:
// per-lane-rare inserts are wave-common, so the screened branch body ran
// at every site; min/max network is cheaper than the exec-mask branch).
// launch_bounds (256,2): (256,3) spilled (round 13, WRITE 31MB). Keep.
__global__ __launch_bounds__(256,2) void k_phase1(
    const float* __restrict__ x, const float* __restrict__ xinv,
    const _Float16* __restrict__ eh0,
    ulonglong2* __restrict__ tri)
{
    __shared__ __align__(16) _Float16 Bs[2][32 * DIM];  // 2 x 16 KB
    const int tid = threadIdx.x;
    const int w = tid >> 6, l = tid & 63;
    const int l15 = l & 15, lhi = l >> 4;
    const int rowbase = (blockIdx.x >> 2) * 256 + w * 64;
    const int kbase   = (blockIdx.x & 3) * 1024;
    char* BsC = (char*)&Bs[0][0];

    // A (row) fragments: lane holds x_norm[row=rowbase+g*16+l15][d=dc*32+lhi*8+j]
    f16x8 a[4][8];
    #pragma unroll
    for (int g = 0; g < 4; g++) {
        int row = rowbase + g*16 + l15;
        float xv = xinv[row];
        const float4* xr = (const float4*)(x + row * DIM);
        #pragma unroll
        for (int dc = 0; dc < 8; dc++) {
            float4 f0 = xr[dc*8 + lhi*2];
            float4 f1 = xr[dc*8 + lhi*2 + 1];
            f16x8 av;
            av[0]=g16(f0.x*xv); av[1]=g16(f0.y*xv);
            av[2]=g16(f0.z*xv); av[3]=g16(f0.w*xv);
            av[4]=g16(f1.x*xv); av[5]=g16(f1.y*xv);
            av[6]=g16(f1.z*xv); av[7]=g16(f1.w*xv);
            a[g][dc] = av;
        }
    }

    // per-lane tracking: slot g <-> row rowbase + g*16 + l15.
    // Track LARGEST dots (m0 >= m1 >= m2) + codes for m0,m1. Branchless.
    float m0[4], m1[4], m2[4];
    unsigned c0[4], c1[4];
    #pragma unroll
    for (int g = 0; g < 4; g++) {
        m0[g] = -INFINITY; m1[g] = -INFINITY; m2[g] = -INFINITY;
        c0[g] = 0xFFFu; c1[g] = 0xFFFu;
    }

    // staging: chunk L = p*256 + w*64 + l holds code row (L&31)=(l&31),
    // source bytes [(L>>5)*16, +16) = p*128 + w*32 + (l>>5)*16 of that row.
    const char* sbase = (const char*)eh0 + (size_t)kbase * 512
                      + (size_t)(l & 31) * 512 + w*32 + (l >> 5)*16;
    auto stage = [&](int kt, int bufbyte) {
        const char* s = sbase + kt * 16384;
        #pragma unroll
        for (int p = 0; p < 4; p++) {
            gload16(s + p*128, BsC + bufbyte + ((p*256 + w*64) << 4));
        }
    };

    // read base: lane (l15,lhi) reads chunk (dc*4+lhi)*32 + ni*16 + l15
    const int rb = lhi*512 + l15*16;
    const f32x4 zc = (f32x4){0.f, 0.f, 0.f, 0.f};

    auto compute = [&](int kt, int bufbyte) {
        f32x4 acc[4][2];
        #pragma unroll
        for (int dc = 0; dc < 8; dc++) {
            #pragma unroll
            for (int ni = 0; ni < 2; ni++) {
                f16x8 b = *(const f16x8*)(BsC + bufbyte + dc*2048 + ni*256 + rb);
                if (dc == 0) {
                    acc[0][ni] = __builtin_amdgcn_mfma_f32_16x16x32_f16(b, a[0][0], zc, 0, 0, 0);
                    acc[1][ni] = __builtin_amdgcn_mfma_f32_16x16x32_f16(b, a[1][0], zc, 0, 0, 0);
                    acc[2][ni] = __builtin_amdgcn_mfma_f32_16x16x32_f16(b, a[2][0], zc, 0, 0, 0);
                    acc[3][ni] = __builtin_amdgcn_mfma_f32_16x16x32_f16(b, a[3][0], zc, 0, 0, 0);
                } else {
                    acc[0][ni] = __builtin_amdgcn_mfma_f32_16x16x32_f16(b, a[0][dc], acc[0][ni], 0, 0, 0);
                    acc[1][ni] = __builtin_amdgcn_mfma_f32_16x16x32_f16(b, a[1][dc], acc[1][ni], 0, 0, 0);
                    acc[2][ni] = __builtin_amdgcn_mfma_f32_16x16x32_f16(b, a[2][dc], acc[2][ni], 0, 0, 0);
                    acc[3][ni] = __builtin_amdgcn_mfma_f32_16x16x32_f16(b, a[3][dc], acc[3][ni], 0, 0, 0);
                }
            }
        }

        // branchless top-3 insertion (max-dot). Ascending code scan + strict >
        // keeps first-min (lowest-code) semantics exactly.
        const int cbase = kbase + kt*32 + lhi*4;
        #pragma unroll
        for (int ni = 0; ni < 2; ni++) {
            #pragma unroll
            for (int g = 0; g < 4; g++) {
                #pragma unroll
                for (int r = 0; r < 4; r++) {
                    float v = acc[g][ni][r];
                    unsigned code = (unsigned)(cbase + ni*16 + r);
                    bool top = v > m0[g];
                    float disp = fminf(m0[g], v);          // displaced from slot 0
                    unsigned dispc = top ? c0[g] : code;
                    m0[g] = fmaxf(m0[g], v);
                    c0[g] = top ? code : c0[g];
                    bool sec = disp > m1[g];
                    float disp2 = fminf(m1[g], disp);      // displaced from slot 1
                    m1[g] = fmaxf(m1[g], disp);
                    c1[g] = sec ? dispc : c1[g];
                    m2[g] = fmaxf(m2[g], disp2);
                }
            }
        }
    };

    stage(0, 0);
    for (int kt = 0; kt < 32; kt += 2) {
        __syncthreads();                    // tile kt staged; prev reads done
        stage(kt + 1, 16384);
        compute(kt, 0);
        __syncthreads();                    // tile kt+1 staged
        if (kt + 2 < 32) stage(kt + 2, 0);
        compute(kt + 1, 16384);
    }

    // convert to u64 keys (dist = 5 - 2*dot; positive; monotone) once
    uint64_t t0[4], t1[4];
    float d2[4];
    #pragma unroll
    for (int g = 0; g < 4; g++) {
        t0[g] = ((uint64_t)fbits(5.0f - 2.0f*m0[g]) << 32) | c0[g];
        t1[g] = ((uint64_t)fbits(5.0f - 2.0f*m1[g]) << 32) | c1[g];
        d2[g] = 5.0f - 2.0f*m2[g];
    }

    // merge across the 4 lhi lane-groups only (2-step butterfly: m=16,32)
    #pragma unroll
    for (int g = 0; g < 4; g++) {
        uint64_t a0 = t0[g], a1 = t1[g];
        float a2 = d2[g];
        #pragma unroll
        for (int m = 16; m < 64; m <<= 1) {
            uint64_t b0 = __shfl_xor(a0, m), b1 = __shfl_xor(a1, m);
            float    b2 = __shfl_xor(a2, m);
            uint64_t lo  = a0 < b0 ? a0 : b0;
            uint64_t hi0 = a0 < b0 ? b0 : a0;
            uint64_t lo1 = a1 < b1 ? a1 : b1;
            uint64_t mid = hi0 > lo1 ? hi0 : lo1;   // 3rd of the 4 keys
            a1 = hi0 < lo1 ? hi0 : lo1;
            a0 = lo;
            a2 = fminf(fminf(a2, b2), bitsf((unsigned)(mid >> 32)));
        }
        t0[g] = a0; t1[g] = a1; d2[g] = a2;
    }

    if (lhi == 0) {
        const int split = blockIdx.x & 3;
        #pragma unroll
        for (int g = 0; g < 4; g++) {
            int row = rowbase + g*16 + l15;
            float d0 = bitsf((unsigned)(t0[g] >> 32));
            uint64_t flag = (d2[g] - d0 < MARGIN1) ? (1ull << 12) : 0ull;
            ulonglong2 ent;
            ent.x = t0[g];
            ent.y = t1[g] | flag;
            tri[(row << 2) | split] = ent;
        }
    }
}

// merge 4 K-splits per row: exact global top-2 + 3rd-of-8 estimate + flags.
__global__ __launch_bounds__(256) void k_merge(
    const ulonglong2* __restrict__ tri,
    int* __restrict__ idx,
    int* __restrict__ rca, int2* __restrict__ rla,
    int* __restrict__ rcb, int* __restrict__ rlb)
{
    int row = blockIdx.x * 256 + threadIdx.x;
    ulonglong2 e0 = tri[row*4 + 0];
    ulonglong2 e1 = tri[row*4 + 1];
    ulonglong2 e2 = tri[row*4 + 2];
    ulonglong2 e3 = tri[row*4 + 3];

    uint64_t c0 = e0.x, c1 = e0.y & ~0x1000ull;
    float c2 = INFINITY;
    auto fold = [&](uint64_t b0, uint64_t b1) {
        b1 &= ~0x1000ull;                         // strip flag bit for ordering
        uint64_t lo  = c0 < b0 ? c0 : b0;
        uint64_t hi0 = c0 < b0 ? b0 : c0;
        uint64_t lo1 = c1 < b1 ? c1 : b1;
        uint64_t mid = hi0 > lo1 ? hi0 : lo1;
        c1 = hi0 < lo1 ? hi0 : lo1;
        c0 = lo;
        c2 = fminf(c2, bitsf((unsigned)(mid >> 32)));
    };
    fold(e1.x, e1.y);
    fold(e2.x, e2.y);
    fold(e3.x, e3.y);

    int k0 = (int)((unsigned)c0 & 0xFFFu);
    idx[row] = k0;
    float d0 = bitsf((unsigned)(c0 >> 32));
    float d1 = bitsf((unsigned)(c1 >> 32));
    bool lA = (d1 - d0 < MARGIN1);
    bool lB = (c2 - d0 < MARGIN1);
    if ((e0.y >> 12) & 1) lB |= (bitsf((unsigned)(e0.x >> 32)) - d0 < MARGIN1);
    if ((e1.y >> 12) & 1) lB |= (bitsf((unsigned)(e1.x >> 32)) - d0 < MARGIN1);
    if ((e2.y >> 12) & 1) lB |= (bitsf((unsigned)(e2.x >> 32)) - d0 < MARGIN1);
    if ((e3.y >> 12) & 1) lB |= (bitsf((unsigned)(e3.x >> 32)) - d0 < MARGIN1);

    if (lA) {
        int k1 = (int)((unsigned)c1 & 0xFFFu);
        int p = atomicAdd(rca, 1);
        if (p < NPTS) rla[p] = make_int2(row, k0 | (k1 << 12));
    }
    if (lB) {
        int q = atomicAdd(rcb, 1);
        if (q < CAPB) rlb[q] = row;
    }
}

// transposed normalized codebook (after k_merge; overwrites EH0+TRI region)
__global__ __launch_bounds__(256) void k_transpose(const float* __restrict__ emb,
                                                   const float* __restrict__ einv,
                                                   float* __restrict__ embT) {
    __shared__ float tile[64][65];
    const int tid = threadIdx.x;
    const int kb = (blockIdx.x & 63) * 64;
    const int db = (blockIdx.x >> 6) * 64;
    #pragma unroll
    for (int s = 0; s < 16; s++) {
        int i = s * 256 + tid;
        int lk = i >> 6, ld = i & 63;
        tile[lk][ld] = emb[(kb + lk) * DIM + db + ld] * einv[kb + lk];
    }
    __syncthreads();
    #pragma unroll
    for (int s = 0; s < 16; s++) {
        int i = s * 256 + tid;
        int ld = i >> 6, lk = i & 63;
        embT[(db + ld) * KCB + kb + lk] = tile[lk][ld];
    }
}

// tier 2a: f64 rescore of the 2 provable candidates, one wave per flagged row
__global__ __launch_bounds__(256) void k_cand(
    const float* __restrict__ x, const float* __restrict__ emb,
    const float* __restrict__ xinv, const float* __restrict__ einv,
    const float* __restrict__ sume,
    const int* __restrict__ rca, const int2* __restrict__ rla,
    int* __restrict__ idx)
{
    int cnt = *rca; if (cnt > NPTS) cnt = NPTS;
    const int w = threadIdx.x >> 6, l = threadIdx.x & 63;
    for (int r = blockIdx.x * 4 + w; r < cnt; r += gridDim.x * 4) {
        int2 ent = rla[r];
        int row = ent.x;
        int k0 = ent.y & 0xFFF, k1 = (ent.y >> 12) & 0xFFF;
        float xv = xinv[row];
        float4 xf = ((const float4*)x)[row * 64 + l];
        double x0 = (double)xf.x * (double)xv, x1 = (double)xf.y * (double)xv;
        double x2 = (double)xf.z * (double)xv, x3 = (double)xf.w * (double)xv;
        int ks[2] = {k0, k1};
        double d[2];
        #pragma unroll
        for (int c = 0; c < 2; c++) {
            int k = ks[c];
            float ev = einv[k];
            float4 e4 = ((const float4*)emb)[k * 64 + l];
            d[c] = x0 * (double)(e4.x * ev) + x1 * (double)(e4.y * ev)
                 + x2 * (double)(e4.z * ev) + x3 * (double)(e4.w * ev);
        }
        #pragma unroll
        for (int o = 32; o; o >>= 1) {
            d[0] += __shfl_xor(d[0], o);
            d[1] += __shfl_xor(d[1], o);
        }
        if (l == 0) {
            double dist0 = 4.0 + (double)sume[k0] - 2.0 * d[0];
            double dist1 = 4.0 + (double)sume[k1] - 2.0 * d[1];
            uint64_t key0 = (dbits(dist0) & 0xFFFFFFFFFFFFF000ull) | (unsigned)k0;
            uint64_t key1 = (dbits(dist1) & 0xFFFFFFFFFFFFF000ull) | (unsigned)k1;
            idx[row] = (int)((key0 < key1 ? key0 : key1) & 0xFFFull);
        }
    }
}

__global__ __launch_bounds__(256) void k_binit(uint64_t* __restrict__ bestu) {
    bestu[blockIdx.x * 256 + threadIdx.x] = ~0ull;
}

// tier 2b: full-K f64, shuffle-free coalesced, block=(row,chunk), atomicMin
__global__ __launch_bounds__(256) void k_full(
    const float* __restrict__ x, const float* __restrict__ embT,
    const float* __restrict__ xinv, const float* __restrict__ sume,
    const int* __restrict__ rcb, const int* __restrict__ rlb,
    uint64_t* __restrict__ bestu)
{
    __shared__ float xs[DIM];
    int cnt = *rcb; if (cnt > CAPB) cnt = CAPB; if (cnt <= 0) return;
    int items = cnt * 16;
    const int tid = threadIdx.x;
    for (int item = blockIdx.x; item < items; item += gridDim.x) {
        int r = item >> 4, chunk = item & 15;
        int row = rlb[r];
        __syncthreads();
        xs[tid] = x[row * DIM + tid] * xinv[row];
        __syncthreads();
        int k = chunk * 256 + tid;
        const float* et = embT + k;
        double dp0 = 0, dp1 = 0, dp2 = 0, dp3 = 0;
        #pragma unroll 8
        for (int d = 0; d < DIM; d += 4) {
            dp0 += (double)xs[d+0] * (double)et[(d+0) * KCB];
            dp1 += (double)xs[d+1] * (double)et[(d+1) * KCB];
            dp2 += (double)xs[d+2] * (double)et[(d+2) * KCB];
            dp3 += (double)xs[d+3] * (double)et[(d+3) * KCB];
        }
        double dist = 4.0 + (double)sume[k] - 2.0 * ((dp0 + dp1) + (dp2 + dp3));
        uint64_t key = (dbits(dist) & 0xFFFFFFFFFFFFF000ull) | (unsigned)k;
        atomicMin((unsigned long long*)&bestu[r], (unsigned long long)key);
    }
}

__global__ __launch_bounds__(256) void k_ffin(const int* __restrict__ rcb,
                                              const int* __restrict__ rlb,
                                              const uint64_t* __restrict__ bestu,
                                              int* __restrict__ idx) {
    int cnt = *rcb; if (cnt > CAPB) cnt = CAPB;
    int i = blockIdx.x * 256 + threadIdx.x;
    if (i < cnt) idx[rlb[i]] = (int)(bestu[i] & 0xFFFull);
}

// gather raw embeddings, straight-through output, loss partials, idx-as-float
__global__ __launch_bounds__(256) void k_gather(const float* __restrict__ x,
                                                const float* __restrict__ emb,
                                                const int* __restrict__ idx,
                                                float* __restrict__ out,
                                                float* __restrict__ lossp) {
    int t = blockIdx.x * 256 + threadIdx.x;
    float ls = 0.f;
    #pragma unroll
    for (int s = 0; s < 4; ++s) {
        int i4 = t + s * 524288;
        int n = i4 >> 6, c4 = i4 & 63;
        int id = idx[n];
        float4 f = ((const float4*)x)[i4];
        float4 q = ((const float4*)emb)[id * 64 + c4];
        float dx = q.x - f.x, dy = q.y - f.y, dz = q.z - f.z, dw = q.w - f.w;
        float4 o = make_float4(f.x + dx, f.y + dy, f.z + dz, f.w + dw);
        ((float4*)out)[i4] = o;
        ls += dx*dx + dy*dy + dz*dz + dw*dw;
        if (c4 == 0) out[NQ + 1 + n] = (float)id;
    }
    #pragma unroll
    for (int o = 32; o; o >>= 1) ls += __shfl_xor(ls, o);
    __shared__ float wsum[4];
    int wid = threadIdx.x >> 6, lane = threadIdx.x & 63;
    if (lane == 0) wsum[wid] = ls;
    __syncthreads();
    if (threadIdx.x == 0) lossp[blockIdx.x] = wsum[0] + wsum[1] + wsum[2] + wsum[3];
}

__global__ __launch_bounds__(256) void k_finalize(const float* __restrict__ lossp,
                                                  float* __restrict__ out) {
    double s = 0;
    for (int i = threadIdx.x; i < 2048; i += 256) s += (double)lossp[i];
    #pragma unroll
    for (int o = 32; o; o >>= 1) s += __shfl_xor(s, o);
    __shared__ double wd[4];
    int wid = threadIdx.x >> 6, lane = threadIdx.x & 63;
    if (lane == 0) wd[wid] = s;
    __syncthreads();
    if (threadIdx.x == 0)
        out[NQ] = (float)(0.25 * ((wd[0] + wd[1] + wd[2] + wd[3]) / (double)NQ));
}

extern "C" void kernel_launch(void* const* d_in, const int* in_sizes, int n_in,
                              void* d_out, int out_size, void* d_ws, size_t ws_size,
                              hipStream_t stream) {
    const float* x   = (const float*)d_in[0];
    const float* emb = (const float*)d_in[1];
    char* ws = (char*)d_ws;
    _Float16* eh0 = (_Float16*)(ws + WS_EH0);
    ulonglong2* tri = (ulonglong2*)(ws + WS_TRI);
    float* embT  = (float*)(ws + WS_EMBT);
    float* sume  = (float*)(ws + WS_SUME);
    float* einv  = (float*)(ws + WS_EINV);
    float* xinv  = (float*)(ws + WS_XINV);
    int*   idx   = (int*)  (ws + WS_IDX);
    int*   rca   = (int*)  (ws + WS_RCA);
    int2*  rla   = (int2*) (ws + WS_RLA);
    int*   rcb   = (int*)  (ws + WS_RCB);
    int*   rlb   = (int*)  (ws + WS_RLB);
    uint64_t* bestu = (uint64_t*)(ws + WS_BEST);
    float* lossp = (float*)(ws + WS_LOSSP);
    float* out = (float*)d_out;

    hipLaunchKernelGGL(k_init,     dim3(1),          dim3(64),  0, stream, rca, rcb);
    hipLaunchKernelGGL(k_norm_x,   dim3(NPTS/4),     dim3(256), 0, stream, x, xinv);
    hipLaunchKernelGGL(k_norm_e,   dim3(KCB/4),      dim3(256), 0, stream, emb, eh0, sume, einv);
    hipLaunchKernelGGL(k_phase1,   dim3(NPTS/256*4), dim3(256), 0, stream,
                       x, xinv, eh0, tri);
    hipLaunchKernelGGL(k_merge,    dim3(NPTS/256),   dim3(256), 0, stream,
                       tri, idx, rca, rla, rcb, rlb);
    hipLaunchKernelGGL(k_transpose,dim3(256),        dim3(256), 0, stream, emb, einv, embT);
    hipLaunchKernelGGL(k_binit,    dim3(CAPB/256),   dim3(256), 0, stream, bestu);
    hipLaunchKernelGGL(k_cand,     dim3(1024),       dim3(256), 0, stream,
                       x, emb, xinv, einv, sume, rca, rla, idx);
    hipLaunchKernelGGL(k_full,     dim3(2048),       dim3(256), 0, stream,
                       x, embT, xinv, sume, rcb, rlb, bestu);
    hipLaunchKernelGGL(k_ffin,     dim3(16),         dim3(256), 0, stream, rcb, rlb, bestu, idx);
    hipLaunchKernelGGL(k_gather,   dim3(2048),       dim3(256), 0, stream,
                       x, emb, idx, out, lossp);
    hipLaunchKernelGGL(k_finalize, dim3(1),          dim3(256), 0, stream, lossp, out);
}

// Round 17
// 177.836 us; speedup vs baseline: 1.1892x; 1.1892x over previous
//
#include <hip/hip_runtime.h>
#include <math.h>
#include <stdint.h>
#include <limits.h>

#define NPTS 32768
#define DIM  256
#define KCB  4096
#define NQ   (NPTS*DIM)

#define EPSN    1e-12f
#define MARGIN1 6.0e-4f
#define F16MIN  6.103515625e-05f
#define CAPB    4096
#define KINIT   0x7F800000FFFFFFFFull   /* packed (+INF, k=~0) */

typedef __attribute__((ext_vector_type(8))) _Float16 f16x8;
typedef __attribute__((ext_vector_type(4))) _Float16 f16x4;
typedef __attribute__((ext_vector_type(4))) float    f32x4;

// ws layout (byte offsets).
// [0,2MB): EH0 f16 codebook; [2MB,4MB): TRI (phase1 out, merge in)
#define WS_EH0   0u
#define WS_TRI   2097152u
#define WS_SUME  4194304u
#define WS_EINV  4210688u
#define WS_XINV  4227072u
#define WS_IDX   4358144u
#define WS_RCA   4489216u
#define WS_RLA   4489232u
#define WS_RCB   4751376u
#define WS_RLB   4751392u
#define WS_BEST  4882464u
#define WS_LOSSP 4915232u

__device__ inline unsigned fbits(float f){ union{float f;unsigned u;}v; v.f=f; return v.u; }
__device__ inline float bitsf(unsigned u){ union{float f;unsigned u;}v; v.u=u; return v.f; }
__device__ inline uint64_t dbits(double d){ union{double d;uint64_t u;}v; v.d=d; return v.u; }
__device__ inline _Float16 g16(float v){
    return (fabsf(v) < F16MIN) ? (_Float16)0.0f : (_Float16)v;
}
__device__ inline void gload16(const void* src, void* lds){
    __builtin_amdgcn_global_load_lds((const __attribute__((address_space(1))) void*)src,
                                     (__attribute__((address_space(3))) void*)lds, 16, 0, 0);
}

__global__ __launch_bounds__(256) void k_norm_x(const float* __restrict__ x,
                                                float* __restrict__ xinv) {
    int w = threadIdx.x >> 6, l = threadIdx.x & 63;
    int row = blockIdx.x * 4 + w;
    float4 v = ((const float4*)x)[row * 64 + l];
    float s = v.x*v.x + v.y*v.y + v.z*v.z + v.w*v.w;
    #pragma unroll
    for (int o = 32; o; o >>= 1) s += __shfl_xor(s, o);
    if (l == 0) xinv[row] = 1.0f / fmaxf(sqrtf(s), EPSN);
}

// also zeroes flag counters (block 0) and inits bestu (blocks 0..15)
__global__ __launch_bounds__(256) void k_norm_e(const float* __restrict__ e,
                                                _Float16* __restrict__ eh0,
                                                float* __restrict__ sume,
                                                float* __restrict__ einv,
                                                int* __restrict__ rca,
                                                int* __restrict__ rcb,
                                                uint64_t* __restrict__ bestu) {
    if (blockIdx.x == 0 && threadIdx.x == 0) { *rca = 0; *rcb = 0; }
    if (blockIdx.x < 16) bestu[blockIdx.x * 256 + threadIdx.x] = ~0ull;
    int w = threadIdx.x >> 6, l = threadIdx.x & 63;
    int row = blockIdx.x * 4 + w;
    float4 v = ((const float4*)e)[row * 64 + l];
    float s = v.x*v.x + v.y*v.y + v.z*v.z + v.w*v.w;
    #pragma unroll
    for (int o = 32; o; o >>= 1) s += __shfl_xor(s, o);
    float inv = 1.0f / fmaxf(sqrtf(s), EPSN);
    float4 n = make_float4(v.x*inv, v.y*inv, v.z*inv, v.w*inv);
    f16x4 h0; h0[0]=g16(n.x); h0[1]=g16(n.y); h0[2]=g16(n.z); h0[3]=g16(n.w);
    ((f16x4*)eh0)[row * 64 + l] = h0;
    float s2 = n.x*n.x + n.y*n.y + n.z*n.z + n.w*n.w;
    #pragma unroll
    for (int o = 32; o; o >>= 1) s2 += __shfl_xor(s2, o);
    if (l == 0) { sume[row] = s2; einv[row] = inv; }
}

// tier 1: swapped-operand f16 MFMA argmin, dhl-major conflict-free LDS,
// constant-bias (5.0) max-screened epilogue, zero-C acc init. (Round-14
// exact code — best measured: 132us. Branchless variant regressed: r16.)
// launch_bounds (256,2): (256,3) spilled (round 13, WRITE 31MB). Keep.
__global__ __launch_bounds__(256,2) void k_phase1(
    const float* __restrict__ x, const float* __restrict__ xinv,
    const _Float16* __restrict__ eh0,
    ulonglong2* __restrict__ tri)
{
    __shared__ __align__(16) _Float16 Bs[2][32 * DIM];  // 2 x 16 KB
    const int tid = threadIdx.x;
    const int w = tid >> 6, l = tid & 63;
    const int l15 = l & 15, lhi = l >> 4;
    const int rowbase = (blockIdx.x >> 2) * 256 + w * 64;
    const int kbase   = (blockIdx.x & 3) * 1024;
    char* BsC = (char*)&Bs[0][0];

    // A (row) fragments: lane holds x_norm[row=rowbase+g*16+l15][d=dc*32+lhi*8+j]
    f16x8 a[4][8];
    #pragma unroll
    for (int g = 0; g < 4; g++) {
        int row = rowbase + g*16 + l15;
        float xv = xinv[row];
        const float4* xr = (const float4*)(x + row * DIM);
        #pragma unroll
        for (int dc = 0; dc < 8; dc++) {
            float4 f0 = xr[dc*8 + lhi*2];
            float4 f1 = xr[dc*8 + lhi*2 + 1];
            f16x8 av;
            av[0]=g16(f0.x*xv); av[1]=g16(f0.y*xv);
            av[2]=g16(f0.z*xv); av[3]=g16(f0.w*xv);
            av[4]=g16(f1.x*xv); av[5]=g16(f1.y*xv);
            av[6]=g16(f1.z*xv); av[7]=g16(f1.w*xv);
            a[g][dc] = av;
        }
    }

    // per-lane tracking: slot g <-> row rowbase + g*16 + l15
    uint64_t t0[4], t1[4];
    float d2[4];
    #pragma unroll
    for (int g = 0; g < 4; g++) { t0[g]=KINIT; t1[g]=KINIT; d2[g]=INFINITY; }

    // staging: chunk L = p*256 + w*64 + l holds code row (L&31)=(l&31),
    // source bytes [(L>>5)*16, +16) = p*128 + w*32 + (l>>5)*16 of that row.
    const char* sbase = (const char*)eh0 + (size_t)kbase * 512
                      + (size_t)(l & 31) * 512 + w*32 + (l >> 5)*16;
    auto stage = [&](int kt, int bufbyte) {
        const char* s = sbase + kt * 16384;
        #pragma unroll
        for (int p = 0; p < 4; p++) {
            gload16(s + p*128, BsC + bufbyte + ((p*256 + w*64) << 4));
        }
    };

    // read base: lane (l15,lhi) reads chunk (dc*4+lhi)*32 + ni*16 + l15
    const int rb = lhi*512 + l15*16;
    const f32x4 zc = (f32x4){0.f, 0.f, 0.f, 0.f};

    auto compute = [&](int kt, int bufbyte) {
        f32x4 acc[4][2];
        #pragma unroll
        for (int dc = 0; dc < 8; dc++) {
            #pragma unroll
            for (int ni = 0; ni < 2; ni++) {
                f16x8 b = *(const f16x8*)(BsC + bufbyte + dc*2048 + ni*256 + rb);
                if (dc == 0) {
                    acc[0][ni] = __builtin_amdgcn_mfma_f32_16x16x32_f16(b, a[0][0], zc, 0, 0, 0);
                    acc[1][ni] = __builtin_amdgcn_mfma_f32_16x16x32_f16(b, a[1][0], zc, 0, 0, 0);
                    acc[2][ni] = __builtin_amdgcn_mfma_f32_16x16x32_f16(b, a[2][0], zc, 0, 0, 0);
                    acc[3][ni] = __builtin_amdgcn_mfma_f32_16x16x32_f16(b, a[3][0], zc, 0, 0, 0);
                } else {
                    acc[0][ni] = __builtin_amdgcn_mfma_f32_16x16x32_f16(b, a[0][dc], acc[0][ni], 0, 0, 0);
                    acc[1][ni] = __builtin_amdgcn_mfma_f32_16x16x32_f16(b, a[1][dc], acc[1][ni], 0, 0, 0);
                    acc[2][ni] = __builtin_amdgcn_mfma_f32_16x16x32_f16(b, a[2][dc], acc[2][ni], 0, 0, 0);
                    acc[3][ni] = __builtin_amdgcn_mfma_f32_16x16x32_f16(b, a[3][dc], acc[3][ni], 0, 0, 0);
                }
            }
        }

        // epilogue: codebook rows are unit-norm => bias is the constant 5.0
        // (|sume-1| ~ 3e-7 absorbed by MARGIN1). Max-screen per (g,ni).
        #pragma unroll
        for (int ni = 0; ni < 2; ni++) {
            #pragma unroll
            for (int g = 0; g < 4; g++) {
                f32x4 v = acc[g][ni];
                float mx = fmaxf(fmaxf(v[0], v[1]), fmaxf(v[2], v[3]));
                if (5.0f - 2.0f*mx < d2[g]) {
                    #pragma unroll
                    for (int r = 0; r < 4; r++) {
                        float db = 5.0f - 2.0f*v[r];            // positive
                        if (db < d2[g]) {
                            int code = kbase + kt*32 + ni*16 + lhi*4 + r;
                            uint64_t key = ((uint64_t)fbits(db) << 32) | (unsigned)code;
                            if (key < t1[g]) {
                                d2[g] = bitsf((unsigned)(t1[g] >> 32));
                                if (key < t0[g]) { t1[g] = t0[g]; t0[g] = key; }
                                else t1[g] = key;
                            } else {
                                d2[g] = db;
                            }
                        }
                    }
                }
            }
        }
    };

    stage(0, 0);
    for (int kt = 0; kt < 32; kt += 2) {
        __syncthreads();                    // tile kt staged; prev reads done
        stage(kt + 1, 16384);
        compute(kt, 0);
        __syncthreads();                    // tile kt+1 staged
        if (kt + 2 < 32) stage(kt + 2, 0);
        compute(kt + 1, 16384);
    }

    // merge across the 4 lhi lane-groups only (2-step butterfly: m=16,32)
    #pragma unroll
    for (int g = 0; g < 4; g++) {
        uint64_t a0 = t0[g], a1 = t1[g];
        float a2 = d2[g];
        #pragma unroll
        for (int m = 16; m < 64; m <<= 1) {
            uint64_t b0 = __shfl_xor(a0, m), b1 = __shfl_xor(a1, m);
            float    b2 = __shfl_xor(a2, m);
            uint64_t lo  = a0 < b0 ? a0 : b0;
            uint64_t hi0 = a0 < b0 ? b0 : a0;
            uint64_t lo1 = a1 < b1 ? a1 : b1;
            uint64_t mid = hi0 > lo1 ? hi0 : lo1;   // 3rd of the 4 keys
            a1 = hi0 < lo1 ? hi0 : lo1;
            a0 = lo;
            a2 = fminf(fminf(a2, b2), bitsf((unsigned)(mid >> 32)));
        }
        t0[g] = a0; t1[g] = a1; d2[g] = a2;
    }

    if (lhi == 0) {
        const int split = blockIdx.x & 3;
        #pragma unroll
        for (int g = 0; g < 4; g++) {
            int row = rowbase + g*16 + l15;
            float d0 = bitsf((unsigned)(t0[g] >> 32));
            uint64_t flag = (d2[g] - d0 < MARGIN1) ? (1ull << 12) : 0ull;
            ulonglong2 ent;
            ent.x = t0[g];
            ent.y = t1[g] | flag;
            tri[(row << 2) | split] = ent;
        }
    }
}

// merge 4 K-splits per row: exact global top-2 + 3rd-of-8 estimate + flags.
__global__ __launch_bounds__(256) void k_merge(
    const ulonglong2* __restrict__ tri,
    int* __restrict__ idx,
    int* __restrict__ rca, int2* __restrict__ rla,
    int* __restrict__ rcb, int* __restrict__ rlb)
{
    int row = blockIdx.x * 256 + threadIdx.x;
    ulonglong2 e0 = tri[row*4 + 0];
    ulonglong2 e1 = tri[row*4 + 1];
    ulonglong2 e2 = tri[row*4 + 2];
    ulonglong2 e3 = tri[row*4 + 3];

    uint64_t c0 = e0.x, c1 = e0.y & ~0x1000ull;
    float c2 = INFINITY;
    auto fold = [&](uint64_t b0, uint64_t b1) {
        b1 &= ~0x1000ull;                         // strip flag bit for ordering
        uint64_t lo  = c0 < b0 ? c0 : b0;
        uint64_t hi0 = c0 < b0 ? b0 : c0;
        uint64_t lo1 = c1 < b1 ? c1 : b1;
        uint64_t mid = hi0 > lo1 ? hi0 : lo1;
        c1 = hi0 < lo1 ? hi0 : lo1;
        c0 = lo;
        c2 = fminf(c2, bitsf((unsigned)(mid >> 32)));
    };
    fold(e1.x, e1.y);
    fold(e2.x, e2.y);
    fold(e3.x, e3.y);

    int k0 = (int)((unsigned)c0 & 0xFFFu);
    idx[row] = k0;
    float d0 = bitsf((unsigned)(c0 >> 32));
    float d1 = bitsf((unsigned)(c1 >> 32));
    bool lA = (d1 - d0 < MARGIN1);
    bool lB = (c2 - d0 < MARGIN1);
    if ((e0.y >> 12) & 1) lB |= (bitsf((unsigned)(e0.x >> 32)) - d0 < MARGIN1);
    if ((e1.y >> 12) & 1) lB |= (bitsf((unsigned)(e1.x >> 32)) - d0 < MARGIN1);
    if ((e2.y >> 12) & 1) lB |= (bitsf((unsigned)(e2.x >> 32)) - d0 < MARGIN1);
    if ((e3.y >> 12) & 1) lB |= (bitsf((unsigned)(e3.x >> 32)) - d0 < MARGIN1);

    if (lA) {
        int k1 = (int)((unsigned)c1 & 0xFFFu);
        int p = atomicAdd(rca, 1);
        if (p < NPTS) rla[p] = make_int2(row, k0 | (k1 << 12));
    }
    if (lB) {
        int q = atomicAdd(rcb, 1);
        if (q < CAPB) rlb[q] = row;
    }
}

// tier 2a: f64 rescore of the 2 provable candidates, one wave per flagged row
__global__ __launch_bounds__(256) void k_cand(
    const float* __restrict__ x, const float* __restrict__ emb,
    const float* __restrict__ xinv, const float* __restrict__ einv,
    const float* __restrict__ sume,
    const int* __restrict__ rca, const int2* __restrict__ rla,
    int* __restrict__ idx)
{
    int cnt = *rca; if (cnt > NPTS) cnt = NPTS;
    const int w = threadIdx.x >> 6, l = threadIdx.x & 63;
    for (int r = blockIdx.x * 4 + w; r < cnt; r += gridDim.x * 4) {
        int2 ent = rla[r];
        int row = ent.x;
        int k0 = ent.y & 0xFFF, k1 = (ent.y >> 12) & 0xFFF;
        float xv = xinv[row];
        float4 xf = ((const float4*)x)[row * 64 + l];
        double x0 = (double)xf.x * (double)xv, x1 = (double)xf.y * (double)xv;
        double x2 = (double)xf.z * (double)xv, x3 = (double)xf.w * (double)xv;
        int ks[2] = {k0, k1};
        double d[2];
        #pragma unroll
        for (int c = 0; c < 2; c++) {
            int k = ks[c];
            float ev = einv[k];
            float4 e4 = ((const float4*)emb)[k * 64 + l];
            d[c] = x0 * (double)(e4.x * ev) + x1 * (double)(e4.y * ev)
                 + x2 * (double)(e4.z * ev) + x3 * (double)(e4.w * ev);
        }
        #pragma unroll
        for (int o = 32; o; o >>= 1) {
            d[0] += __shfl_xor(d[0], o);
            d[1] += __shfl_xor(d[1], o);
        }
        if (l == 0) {
            double dist0 = 4.0 + (double)sume[k0] - 2.0 * d[0];
            double dist1 = 4.0 + (double)sume[k1] - 2.0 * d[1];
            uint64_t key0 = (dbits(dist0) & 0xFFFFFFFFFFFFF000ull) | (unsigned)k0;
            uint64_t key1 = (dbits(dist1) & 0xFFFFFFFFFFFFF000ull) | (unsigned)k1;
            idx[row] = (int)((key0 < key1 ? key0 : key1) & 0xFFFull);
        }
    }
}

// tier 2b: full-K f64 direct from emb (no transpose): 8 lanes per code,
// coalesced 128B group reads, 3-level shuffle reduce, atomicMin keys.
__global__ __launch_bounds__(256) void k_full(
    const float* __restrict__ x, const float* __restrict__ emb,
    const float* __restrict__ xinv, const float* __restrict__ einv,
    const float* __restrict__ sume,
    const int* __restrict__ rcb, const int* __restrict__ rlb,
    uint64_t* __restrict__ bestu)
{
    __shared__ __align__(16) float xs[DIM];
    int cnt = *rcb; if (cnt > CAPB) cnt = CAPB; if (cnt <= 0) return;
    const int tid = threadIdx.x;
    const int grp = tid >> 3, sub = tid & 7;
    int items = cnt * 16;
    for (int item = blockIdx.x; item < items; item += gridDim.x) {
        int r = item >> 4, chunk = item & 15;
        int row = rlb[r];
        __syncthreads();
        xs[tid] = x[row * DIM + tid] * xinv[row];
        __syncthreads();
        const float4* xs4 = (const float4*)xs;
        uint64_t best = ~0ull;
        #pragma unroll
        for (int j = 0; j < 8; j++) {
            int k = chunk * 256 + grp * 8 + j;
            float ev = einv[k];
            const float4* e4 = (const float4*)(emb + k * DIM);
            double dp = 0;
            #pragma unroll
            for (int i = 0; i < 8; i++) {
                float4 ef = e4[sub + i*8];
                float4 xf = xs4[sub + i*8];
                dp += (double)xf.x * (double)(ef.x * ev)
                    + (double)xf.y * (double)(ef.y * ev)
                    + (double)xf.z * (double)(ef.z * ev)
                    + (double)xf.w * (double)(ef.w * ev);
            }
            #pragma unroll
            for (int o = 4; o; o >>= 1) dp += __shfl_xor(dp, o);
            if (sub == 0) {
                double dist = 4.0 + (double)sume[k] - 2.0 * dp;
                uint64_t key = (dbits(dist) & 0xFFFFFFFFFFFFF000ull) | (unsigned)k;
                best = key < best ? key : best;
            }
        }
        if (sub == 0)
            atomicMin((unsigned long long*)&bestu[r], (unsigned long long)best);
    }
}

__global__ __launch_bounds__(256) void k_ffin(const int* __restrict__ rcb,
                                              const int* __restrict__ rlb,
                                              const uint64_t* __restrict__ bestu,
                                              int* __restrict__ idx) {
    int cnt = *rcb; if (cnt > CAPB) cnt = CAPB;
    int i = blockIdx.x * 256 + threadIdx.x;
    if (i < cnt) idx[rlb[i]] = (int)(bestu[i] & 0xFFFull);
}

// gather raw embeddings, straight-through output, loss partials, idx-as-float
__global__ __launch_bounds__(256) void k_gather(const float* __restrict__ x,
                                                const float* __restrict__ emb,
                                                const int* __restrict__ idx,
                                                float* __restrict__ out,
                                                float* __restrict__ lossp) {
    int t = blockIdx.x * 256 + threadIdx.x;
    float ls = 0.f;
    #pragma unroll
    for (int s = 0; s < 4; ++s) {
        int i4 = t + s * 524288;
        int n = i4 >> 6, c4 = i4 & 63;
        int id = idx[n];
        float4 f = ((const float4*)x)[i4];
        float4 q = ((const float4*)emb)[id * 64 + c4];
        float dx = q.x - f.x, dy = q.y - f.y, dz = q.z - f.z, dw = q.w - f.w;
        float4 o = make_float4(f.x + dx, f.y + dy, f.z + dz, f.w + dw);
        ((float4*)out)[i4] = o;
        ls += dx*dx + dy*dy + dz*dz + dw*dw;
        if (c4 == 0) out[NQ + 1 + n] = (float)id;
    }
    #pragma unroll
    for (int o = 32; o; o >>= 1) ls += __shfl_xor(ls, o);
    __shared__ float wsum[4];
    int wid = threadIdx.x >> 6, lane = threadIdx.x & 63;
    if (lane == 0) wsum[wid] = ls;
    __syncthreads();
    if (threadIdx.x == 0) lossp[blockIdx.x] = wsum[0] + wsum[1] + wsum[2] + wsum[3];
}

__global__ __launch_bounds__(256) void k_finalize(const float* __restrict__ lossp,
                                                  float* __restrict__ out) {
    double s = 0;
    for (int i = threadIdx.x; i < 2048; i += 256) s += (double)lossp[i];
    #pragma unroll
    for (int o = 32; o; o >>= 1) s += __shfl_xor(s, o);
    __shared__ double wd[4];
    int wid = threadIdx.x >> 6, lane = threadIdx.x & 63;
    if (lane == 0) wd[wid] = s;
    __syncthreads();
    if (threadIdx.x == 0)
        out[NQ] = (float)(0.25 * ((wd[0] + wd[1] + wd[2] + wd[3]) / (double)NQ));
}

extern "C" void kernel_launch(void* const* d_in, const int* in_sizes, int n_in,
                              void* d_out, int out_size, void* d_ws, size_t ws_size,
                              hipStream_t stream) {
    const float* x   = (const float*)d_in[0];
    const float* emb = (const float*)d_in[1];
    char* ws = (char*)d_ws;
    _Float16* eh0 = (_Float16*)(ws + WS_EH0);
    ulonglong2* tri = (ulonglong2*)(ws + WS_TRI);
    float* sume  = (float*)(ws + WS_SUME);
    float* einv  = (float*)(ws + WS_EINV);
    float* xinv  = (float*)(ws + WS_XINV);
    int*   idx   = (int*)  (ws + WS_IDX);
    int*   rca   = (int*)  (ws + WS_RCA);
    int2*  rla   = (int2*) (ws + WS_RLA);
    int*   rcb   = (int*)  (ws + WS_RCB);
    int*   rlb   = (int*)  (ws + WS_RLB);
    uint64_t* bestu = (uint64_t*)(ws + WS_BEST);
    float* lossp = (float*)(ws + WS_LOSSP);
    float* out = (float*)d_out;

    hipLaunchKernelGGL(k_norm_x,   dim3(NPTS/4),     dim3(256), 0, stream, x, xinv);
    hipLaunchKernelGGL(k_norm_e,   dim3(KCB/4),      dim3(256), 0, stream,
                       emb, eh0, sume, einv, rca, rcb, bestu);
    hipLaunchKernelGGL(k_phase1,   dim3(NPTS/256*4), dim3(256), 0, stream,
                       x, xinv, eh0, tri);
    hipLaunchKernelGGL(k_merge,    dim3(NPTS/256),   dim3(256), 0, stream,
                       tri, idx, rca, rla, rcb, rlb);
    hipLaunchKernelGGL(k_cand,     dim3(1024),       dim3(256), 0, stream,
                       x, emb, xinv, einv, sume, rca, rla, idx);
    hipLaunchKernelGGL(k_full,     dim3(2048),       dim3(256), 0, stream,
                       x, emb, xinv, einv, sume, rcb, rlb, bestu);
    hipLaunchKernelGGL(k_ffin,     dim3(16),         dim3(256), 0, stream, rcb, rlb, bestu, idx);
    hipLaunchKernelGGL(k_gather,   dim3(2048),       dim3(256), 0, stream,
                       x, emb, idx, out, lossp);
    hipLaunchKernelGGL(k_finalize, dim3(1),          dim3(256), 0, stream, lossp, out);
}